// Round 1
// 788.963 us; speedup vs baseline: 1.0191x; 1.0191x over previous
//
#include <hip/hip_runtime.h>

// R1: fold message projection through GRU input algebraically.
//   m_i = W_mh * (sum_j a_ij h_j) + ec_i            (aggregate-then-project)
//   gi  = (W_ih*W_mh) * hs_i + c_i,  c_i = W_ih*ec_i + b_ih  (layer-invariant)
// -> per layer ONE kernel (was k_hw + k_gru); hw buffer eliminated.
// Predicted: dur 804 -> ~700-740 us; our WRITE_SIZE -2MB; fills unchanged.

__device__ __forceinline__ float sigm(float x){ return 1.f / (1.f + __expf(-x)); }

constexpr int N = 1024, D = 128, CAP = 192;

// workspace layout (float offsets); transposed weights first, contiguously,
// so k_prep can write ws[idx] directly.
constexpr int OFF_WT_ME   = 0;                        // [f][d] 128x128
constexpr int OFF_WT_IH   = OFF_WT_ME   + 128*128;    // [f][o] 128x384 (k_cprep)
constexpr int OFF_WT_HH   = OFF_WT_IH   + 128*384;    // [f][o] 128x384
constexpr int OFF_WT_GATE = OFF_WT_HH   + 128*384;    // [f][c] 256x128
constexpr int OFF_WT_OUT  = OFF_WT_GATE + 256*128;    // [f][c] 256x128
constexpr int OFF_WT_FC   = OFF_WT_OUT  + 256*128;    // [c][o] 256x128
constexpr int OFF_EE      = OFF_WT_FC   + 256*128;    // 128
constexpr int OFF_GV      = OFF_EE + 128;             // 128 (zeroed)
constexpr int OFF_WCT     = OFF_GV + 128;             // [f][o] 128x384 = (W_ih*W_mh)^T
constexpr int OFF_C       = OFF_WCT + 128*384;        // [i][o] 1024x384
constexpr int OFF_EC      = OFF_C   + N*384;          // N*D
constexpr int OFF_HA      = OFF_EC  + N*D;            // N*D (h ping)
constexpr int OFF_HB      = OFF_HA  + N*D;            // N*D (h pong)
constexpr int OFF_CNT     = OFF_HB  + N*D;            // N ints
constexpr int OFF_NZI     = OFF_CNT + N;              // N*CAP ints
constexpr int OFF_NZV     = OFF_NZI + N*CAP;          // N*CAP floats

// prep segment boundaries (== OFF_* because transposes are laid out first)
constexpr int PT0 = OFF_WT_IH, PT1 = OFF_WT_HH, PT2 = OFF_WT_GATE, PT3 = OFF_WT_OUT,
              PT4 = OFF_WT_FC, PT5 = OFF_EE, PT6 = OFF_GV, PT7 = OFF_WCT; // prep end

__global__ __launch_bounds__(256)
void k_prep(const float* w_me, const float* w_ih, const float* w_hh,
            const float* w_gate, const float* w_out, const float* w_fc,
            const float* w_embed, const float* edge, float* ws){
  int idx = blockIdx.x * 256 + threadIdx.x;
  if (idx < PT0)      { int k = idx;       int f = k >> 7, d = k & 127; ws[idx] = w_me[d*128 + f]; }
  else if (idx < PT1) { int k = idx - PT0; int f = k / 384, o = k % 384; ws[idx] = w_ih[o*128 + f]; }
  else if (idx < PT2) { int k = idx - PT1; int f = k / 384, o = k % 384; ws[idx] = w_hh[o*128 + f]; }
  else if (idx < PT3) { int k = idx - PT2; int f = k >> 7, c = k & 127; ws[idx] = w_gate[c*256 + f]; }
  else if (idx < PT4) { int k = idx - PT3; int f = k >> 7, c = k & 127; ws[idx] = w_out[c*256 + f]; }
  else if (idx < PT5) { int k = idx - PT4; int c = k >> 7, o = k & 127; ws[idx] = w_fc[o*256 + c]; }
  else if (idx < PT6) { int c = idx - PT5; float a = 0.f;
                        for (int q = 0; q < 5; ++q) a += w_embed[c*5 + q] * edge[q];
                        ws[idx] = a; }
  else if (idx < PT7) { ws[idx] = 0.f; }  // gv accumulator
}

// WC^T[f][o] = sum_d w_ih[o,d] * w_mh[d,f]  (one-time 384x128x128 matmul)
__global__ __launch_bounds__(128)
void k_wc(const float* w_ih, const float* w_mh, float* ws){
  __shared__ float ih_sh[128];
  const int o = blockIdx.x, t = threadIdx.x;
  ih_sh[t] = w_ih[o*128 + t];
  __syncthreads();
  float acc = 0.f;
  for (int d = 0; d < 128; ++d) acc += ih_sh[d] * w_mh[d*128 + t];  // coalesced in t
  ws[OFF_WCT + t*384 + o] = acc;
}

// One block per graph row i: scan adj row -> nonzero list (persisted for the
// layer loop), gather sparse e rows -> ea, project ec = ea @ w_me^T + b_msg,
// and init h ping buffer.
__global__ __launch_bounds__(256)
void k_gather(const float* adj, const float* e, const float* h, const float* b_msg, float* ws){
  __shared__ int   cnt_sh;
  __shared__ int   idx_sh[CAP];
  __shared__ float val_sh[CAP];
  __shared__ float red_sh[512];
  __shared__ float ea_sh[128];
  const int i = blockIdx.x, t = threadIdx.x;
  if (t == 0) cnt_sh = 0;
  __syncthreads();
  const float* arow = adj + (size_t)i * N;
  #pragma unroll
  for (int q = 0; q < 4; ++q){
    int j = t + q*256;
    float v = arow[j];
    if (v != 0.f){
      int p = atomicAdd(&cnt_sh, 1);
      if (p < CAP){ idx_sh[p] = j; val_sh[p] = v; }
    }
  }
  __syncthreads();
  const int cnt = min(cnt_sh, CAP);
  int*   cntp = (int*)(ws + OFF_CNT);
  int*   nzi  = (int*)(ws + OFF_NZI);
  float* nzv  = ws + OFF_NZV;
  if (t == 0) cntp[i] = cnt;
  for (int k = t; k < cnt; k += 256){ nzi[(size_t)i*CAP + k] = idx_sh[k]; nzv[(size_t)i*CAP + k] = val_sh[k]; }

  // ea[f] = sum_j adj[i,j] * e[i,j,f]; wave wv handles nnz k = wv mod 4,
  // lanes cover the 128-f row as 64 x float2.
  const int lane = t & 63, wv = t >> 6;
  float ax = 0.f, ay = 0.f;
  const float* eb = e + ((size_t)i << 17);   // i*1024*128
  for (int k = wv; k < cnt; k += 4){
    int j = idx_sh[k]; float v = val_sh[k];
    float2 uu = *(const float2*)(eb + (size_t)j*128 + 2*lane);
    ax += v * uu.x;
    ay += v * uu.y;
  }
  red_sh[wv*128 + 2*lane]     = ax;
  red_sh[wv*128 + 2*lane + 1] = ay;
  __syncthreads();
  if (t < 128) ea_sh[t] = red_sh[t] + red_sh[128+t] + red_sh[256+t] + red_sh[384+t];
  __syncthreads();

  // ec[i][d] = b_msg[d] + sum_f ea[f] * w_me[d][f]  (wT_me[f][d], coalesced)
  const float* wT = ws + OFF_WT_ME;
  const int d = t & 127, half = t >> 7;
  float acc = 0.f;
  for (int f = half*64; f < half*64 + 64; ++f) acc += ea_sh[f] * wT[f*128 + d];
  red_sh[half*128 + d] = acc;
  __syncthreads();
  if (t < 128){
    ws[OFF_EC + (size_t)i*128 + t] = red_sh[t] + red_sh[128 + t] + b_msg[t];
    ws[OFF_HA + (size_t)i*128 + t] = h[(size_t)i*128 + t];
  }
}

// c[i][o] = b_ih[o] + sum_d wT_ih[d][o] * ec[i][d]   (layer-invariant GRU input part)
__global__ __launch_bounds__(384)
void k_cprep(const float* b_ih, float* ws){
  __shared__ float ec_sh[4][128];
  const int t = threadIdx.x, i0 = blockIdx.x * 4;
  const float* ec = ws + OFF_EC;
  for (int idx = t; idx < 512; idx += 384){
    int n = idx >> 7, c = idx & 127;
    ec_sh[n][c] = ec[(size_t)(i0+n)*128 + c];
  }
  __syncthreads();
  const float* wi_ = ws + OFF_WT_IH;
  float acc[4] = {};
  for (int f = 0; f < 128; ++f){
    float w = wi_[f*384 + t];
    #pragma unroll
    for (int n = 0; n < 4; ++n) acc[n] += w * ec_sh[n][f];
  }
  const float bi = b_ih[t];
  float* C = ws + OFF_C;
  #pragma unroll
  for (int n = 0; n < 4; ++n) C[(size_t)(i0+n)*384 + t] = acc[n] + bi;
}

// One fused layer: hs = sparse(adj)·hA, gi = WC·hs + c, gh = W_hh·hA[i] + b_hh,
// GRU gates, hB[i] = update. 4 nodes/block.
__global__ __launch_bounds__(384)
void k_layer(const float* b_hh, const float* hA, float* hB, float* ws){
  __shared__ float hs_sh[4][128], h_sh[4][128];
  __shared__ float sr_sh[4][128], sz_sh[4][128], gn_sh[4][128], hn_sh[4][128];
  const int t = threadIdx.x, i0 = blockIdx.x * 4;
  const int*   cntp = (const int*)(ws + OFF_CNT);
  const int*   nzi  = (const int*)(ws + OFF_NZI);
  const float* nzv  = ws + OFF_NZV;
  for (int idx = t; idx < 512; idx += 384){
    int n = idx >> 7, c = idx & 127, i = i0 + n;
    h_sh[n][c] = hA[(size_t)i*128 + c];
    float a = 0.f;
    const int cn = cntp[i];
    const int*   ji = nzi + (size_t)i*CAP;
    const float* jv = nzv + (size_t)i*CAP;
    for (int k = 0; k < cn; ++k) a += jv[k] * hA[(size_t)ji[k]*128 + c];
    hs_sh[n][c] = a;
  }
  __syncthreads();
  const float* wc_ = ws + OFF_WCT;
  const float* wh_ = ws + OFF_WT_HH;
  float ag[4] = {}, ah[4] = {};
  for (int f = 0; f < 128; ++f){
    float wi = wc_[f*384 + t], wh = wh_[f*384 + t];
    #pragma unroll
    for (int n = 0; n < 4; ++n){ ag[n] += wi * hs_sh[n][f]; ah[n] += wh * h_sh[n][f]; }
  }
  const float* C = ws + OFF_C;
  float cv[4];
  #pragma unroll
  for (int n = 0; n < 4; ++n) cv[n] = C[(size_t)(i0+n)*384 + t];
  const float bh = b_hh[t];
  if (t < 128){
    #pragma unroll
    for (int n = 0; n < 4; ++n) sr_sh[n][t] = ag[n] + cv[n] + ah[n] + bh;
  } else if (t < 256){
    const int c = t - 128;
    #pragma unroll
    for (int n = 0; n < 4; ++n) sz_sh[n][c] = ag[n] + cv[n] + ah[n] + bh;
  } else {
    const int c = t - 256;
    #pragma unroll
    for (int n = 0; n < 4; ++n){ gn_sh[n][c] = ag[n] + cv[n]; hn_sh[n][c] = ah[n] + bh; }
  }
  __syncthreads();
  for (int idx = t; idx < 512; idx += 384){
    int n = idx >> 7, c = idx & 127;
    float r  = sigm(sr_sh[n][c]);
    float z  = sigm(sz_sh[n][c]);
    float nn = tanhf(gn_sh[n][c] + r * hn_sh[n][c]);
    hB[(size_t)(i0+n)*128 + c] = (1.f - z) * nn + z * h_sh[n][c];
  }
}

// gated-sum readout: per 8 nodes compute sig(hc@Wg^T+bg)*tanh(hc@Wo^T+bo), atomicAdd into gv
__global__ __launch_bounds__(128)
void k_readout(const float* h0, const float* b_gate, const float* b_out, float* ws){
  __shared__ float hc_sh[8][256];
  const int t = threadIdx.x, i0 = blockIdx.x * 8;
  const float* hcur = ws + OFF_HA;   // final h lands in ping buffer after 4 layers
  #pragma unroll
  for (int n = 0; n < 8; ++n){
    hc_sh[n][t]       = hcur[(size_t)(i0+n)*128 + t];
    hc_sh[n][128 + t] = h0[(size_t)(i0+n)*128 + t];
  }
  __syncthreads();
  const float* wg_ = ws + OFF_WT_GATE;
  const float* wo_ = ws + OFF_WT_OUT;
  float ag[8] = {}, ao[8] = {};
  for (int f = 0; f < 256; ++f){
    float wg = wg_[f*128 + t], wo = wo_[f*128 + t];
    #pragma unroll
    for (int n = 0; n < 8; ++n){ ag[n] += wg * hc_sh[n][f]; ao[n] += wo * hc_sh[n][f]; }
  }
  const float bg = b_gate[t], bo = b_out[t];
  float s = 0.f;
  #pragma unroll
  for (int n = 0; n < 8; ++n) s += sigm(ag[n] + bg) * tanhf(ao[n] + bo);
  atomicAdd(ws + OFF_GV + t, s);
}

__global__ __launch_bounds__(128)
void k_fc(const float* b_fc, float* out, const float* ws){
  const int o = threadIdx.x;
  const float* wT = ws + OFF_WT_FC;
  const float* gv = ws + OFF_GV;
  const float* ee = ws + OFF_EE;
  float acc = b_fc[o];
  for (int c = 0; c < 128; ++c) acc += gv[c] * wT[c*128 + o];
  for (int c = 0; c < 128; ++c) acc += ee[c] * wT[(128 + c)*128 + o];
  out[o] = acc;
}

extern "C" void kernel_launch(void* const* d_in, const int* in_sizes, int n_in,
                              void* d_out, int out_size, void* d_ws, size_t ws_size,
                              hipStream_t stream){
  const float* h      = (const float*)d_in[0];
  const float* e      = (const float*)d_in[1];
  const float* adj    = (const float*)d_in[2];
  const float* edge   = (const float*)d_in[3];
  const float* w_mh   = (const float*)d_in[4];
  const float* w_me   = (const float*)d_in[5];
  const float* b_msg  = (const float*)d_in[6];
  const float* w_ih   = (const float*)d_in[7];
  const float* w_hh   = (const float*)d_in[8];
  const float* b_ih   = (const float*)d_in[9];
  const float* b_hh   = (const float*)d_in[10];
  const float* w_gate = (const float*)d_in[11];
  const float* b_gate = (const float*)d_in[12];
  const float* w_out  = (const float*)d_in[13];
  const float* b_out  = (const float*)d_in[14];
  const float* w_emb  = (const float*)d_in[15];
  const float* w_fc   = (const float*)d_in[16];
  const float* b_fc   = (const float*)d_in[17];
  float* ws = (float*)d_ws;

  k_prep<<<(PT7 + 255) / 256, 256, 0, stream>>>(w_me, w_ih, w_hh, w_gate, w_out,
                                                w_fc, w_emb, edge, ws);
  k_wc<<<384, 128, 0, stream>>>(w_ih, w_mh, ws);
  k_gather<<<N, 256, 0, stream>>>(adj, e, h, b_msg, ws);
  k_cprep<<<N/4, 384, 0, stream>>>(b_ih, ws);
  float* hA = ws + OFF_HA;
  float* hB = ws + OFF_HB;
  for (int l = 0; l < 4; ++l){
    const float* src = (l & 1) ? hB : hA;
    float*       dst = (l & 1) ? hA : hB;
    k_layer<<<N/4, 384, 0, stream>>>(b_hh, src, dst, ws);
  }
  k_readout<<<N/8, 128, 0, stream>>>(h, b_gate, b_out, ws);
  k_fc<<<1, 128, 0, stream>>>(b_fc, (float*)d_out, ws);
}